// Round 10
// baseline (302.418 us; speedup 1.0000x reference)
//
#include <hip/hip_runtime.h>
#include <hip/hip_fp16.h>
#include <cmath>

#define BATCH 16
#define NID   15
#define NSEG  240
#define HW    262144          // 512*512
#define HEADB 65536
#define NSPL  16              // pixel splits in hist
#define SEGPC 8               // segments per hist chunk (chunks: 8 + 7)
#define PREBLK 1024           // pre blocks (64 per batch, 4096 px each)
#define PSTRIDE 112           // floats per pre-block partial record

// compact key space for d = exp(-arg) in [0,1], SH=16 (~0.54% relative width)
#define KFINEBASE 15232       // 0x3B800000 >> 16
#define KOVF 119
#define KTOT 1144             // 119 + 1025

__device__ __forceinline__ int keyof(float d) {
  unsigned b = __float_as_uint(d);
  return (b >= 0x3B800000u) ? (int)((b >> 16) - KFINEBASE + KOVF) : (int)(b >> 23);
}
__device__ __forceinline__ void boundsof(int k, float* lo, float* hi) {
  if (k >= KOVF) {
    unsigned u = (unsigned)(k - KOVF + KFINEBASE) << 16;
    *lo = __uint_as_float(u);
    *hi = __uint_as_float(u + 65536u);
  } else {
    *lo = __uint_as_float((unsigned)k << 23);
    *hi = __uint_as_float((unsigned)(k + 1) << 23);
  }
}

__device__ __forceinline__ float fast_tanh(float x) {
  float e = __expf(2.0f * x);
  return 1.0f - 2.0f / (e + 1.0f);
}
__device__ __forceinline__ float fast_sigmoid(float x) {
  return 1.0f / (1.0f + __expf(-x));
}

struct Params { float cx, cy, e0, e1, var, valid, cnt; };
__device__ __forceinline__ Params calc_params(const float* __restrict__ st) {
  Params p;
  float cnt = st[0];
  float safe = fmaxf(cnt, 1.0f);
  p.cx = st[1] / safe;
  p.cy = st[2] / safe;
  float m0 = st[3] / safe, m1 = st[4] / safe;
  float v0 = st[5] - 2.0f * m0 * (m0 * safe) + m0 * m0 * cnt;
  float v1 = st[6] - 2.0f * m1 * (m1 * safe) + m1 * m1 * cnt;
  p.var = (v0 + v1) / (2.0f * safe);
  p.e0 = expf(10.0f * m0);
  p.e1 = expf(10.0f * m1);
  p.valid = (cnt > 0.f) ? 1.f : 0.f;
  p.cnt = cnt;
  return p;
}

// ---------------- pre: register-accumulated stats (no per-pixel LDS/global atomics) ----------------
__global__ void __launch_bounds__(256, 2)
pre_kernel(const float* __restrict__ pred, const int* __restrict__ inst,
           const int* __restrict__ lab, float* __restrict__ blockpart,
           unsigned* __restrict__ exyh, unsigned* __restrict__ tb8,
           unsigned* __restrict__ sd8) {
  __shared__ float ws[4][NID * 7 + 1];
  int tid = threadIdx.x;
  int w = tid >> 6, lane = tid & 63;
  int gid = blockIdx.x;
  int b = gid >> 6, c = gid & 63;      // 64 blocks per batch, 4096 px per block
  const float* pb = pred + (size_t)b * 5 * HW;
  const int4* ip = (const int4*)(inst + (size_t)b * HW);
  const int4* lp = (const int4*)(lab + (size_t)b * HW);
  size_t bq = (size_t)b * (HW / 4);
  float acc[NID][7];
#pragma unroll
  for (int id = 0; id < NID; ++id)
#pragma unroll
    for (int s = 0; s < 7; ++s) acc[id][s] = 0.f;
  float bgacc = 0.f;
  for (int it = 0; it < 4; ++it) {
    int g = c * 1024 + it * 256 + tid;
    float4 v0 = ((const float4*)pb)[g];
    float4 v1 = ((const float4*)(pb + HW))[g];
    float4 v2 = ((const float4*)(pb + 2 * HW))[g];
    float4 v3 = ((const float4*)(pb + 3 * HW))[g];
    float4 v4 = ((const float4*)(pb + 4 * HW))[g];
    int4 t4 = ip[g];
    int4 l4 = lp[g];
    float p0a[4] = {v0.x, v0.y, v0.z, v0.w};
    float p1a[4] = {v1.x, v1.y, v1.z, v1.w};
    float p2a[4] = {v2.x, v2.y, v2.z, v2.w};
    float p3a[4] = {v3.x, v3.y, v3.z, v3.w};
    float p4a[4] = {v4.x, v4.y, v4.z, v4.w};
    int ta[4] = {t4.x, t4.y, t4.z, t4.w};
    int la[4] = {l4.x, l4.y, l4.z, l4.w};
    unsigned eo[4], tpack = 0, spack = 0;
    int px0 = g * 4;
#pragma unroll
    for (int k = 0; k < 4; ++k) {
      int px = px0 + k;
      float xm = (float)(px & 511) * (1.0f / 511.0f);
      float ym = (float)(px >> 9) * (1.0f / 511.0f);
      float ex = fast_tanh(p0a[k]) + xm;
      float ey = fast_tanh(p1a[k]) + ym;
      float sd = fast_sigmoid(p4a[k]);
      __half2 h = __floats2half2_rn(ex, ey);
      eo[k] = *reinterpret_cast<unsigned*>(&h);
      int t = ta[k];
      tpack |= ((unsigned)(t & 255)) << (8 * k);
      unsigned sq = (unsigned)(sd * 255.0f + 0.5f);
      spack |= (sq & 255u) << (8 * k);
      float p2 = p2a[k], p3 = p3a[k];
      float q2 = p2 * p2, q3 = p3 * p3;
#pragma unroll
      for (int id = 0; id < NID; ++id) {
        float pr = (t == id + 1) ? 1.0f : 0.0f;
        acc[id][0] += pr;
        acc[id][1] += pr * ex;
        acc[id][2] += pr * ey;
        acc[id][3] += pr * p2;
        acc[id][4] += pr * p3;
        acc[id][5] += pr * q2;
        acc[id][6] += pr * q3;
      }
      if (la[k] == 0) bgacc += sd * sd;
    }
    ((uint4*)exyh)[bq + g] = make_uint4(eo[0], eo[1], eo[2], eo[3]);
    tb8[bq + g] = tpack;
    sd8[bq + g] = spack;
  }
#pragma unroll
  for (int id = 0; id < NID; ++id)
#pragma unroll
    for (int s = 0; s < 7; ++s) {
      float v = acc[id][s];
      for (int off = 32; off > 0; off >>= 1) v += __shfl_down(v, off, 64);
      if (lane == 0) ws[w][id * 7 + s] = v;
    }
  for (int off = 32; off > 0; off >>= 1) bgacc += __shfl_down(bgacc, off, 64);
  if (lane == 0) ws[w][NID * 7] = bgacc;
  __syncthreads();
  float* bp = blockpart + (size_t)gid * PSTRIDE;
  for (int i = tid; i < NID * 7 + 1; i += 256)
    bp[i] = ws[0][i] + ws[1][i] + ws[2][i] + ws[3][i];
}

// ---------------- reduce pre partials (64 blocks/batch) -> stats, seedbg ----------------
__global__ void reduce_kernel(const float* __restrict__ blockpart, float* __restrict__ stats,
                              float* __restrict__ seedbg) {
  int s = blockIdx.x;       // 0..105
  int b = blockIdx.y;
  int tid = threadIdx.x;    // 64
  float v = blockpart[(size_t)(b * 64 + tid) * PSTRIDE + s];
  for (int off = 32; off > 0; off >>= 1) v += __shfl_down(v, off, 64);
  if (tid == 0) {
    if (s < NID * 7) {
      int id = s / 7, st = s % 7;
      stats[(b * NID + id) * 8 + st] = v;
    } else {
      seedbg[b] = v;
    }
  }
}

// ---------------- hist: 8 segments per block, packed pos|neg LDS histograms ----------------
__global__ void __launch_bounds__(512)
hist_kernel(const unsigned* __restrict__ exyh, const unsigned* __restrict__ tb8,
            const unsigned* __restrict__ sd8, const float* __restrict__ stats,
            unsigned* __restrict__ partPN, float* __restrict__ seedi) {
  int split = blockIdx.x;       // 0..15
  int chunk = blockIdx.y;       // 0..1
  int b = blockIdx.z;           // 0..15
  int seg0 = chunk * SEGPC;     // 0 or 8; segs seg0..seg0+7 (last chunk has 7)
  __shared__ unsigned lhist[SEGPC * KTOT];   // 36.6 KB
  __shared__ float prm[SEGPC][5];
  int tid = threadIdx.x;
  if (tid < SEGPC) {
    int gs = seg0 + tid;
    if (gs < NID) {
      Params pp = calc_params(stats + (size_t)(b * NID + gs) * 8);
      prm[tid][0] = pp.cx; prm[tid][1] = pp.cy; prm[tid][2] = pp.e0; prm[tid][3] = pp.e1;
      prm[tid][4] = pp.valid;
    } else {
      prm[tid][4] = 0.f;
    }
  }
  for (int k = tid; k < SEGPC * KTOT; k += 512) lhist[k] = 0u;
  __syncthreads();
  float cxr[SEGPC], cyr[SEGPC], e0r[SEGPC], e1r[SEGPC];
  bool vr[SEGPC];
#pragma unroll
  for (int n = 0; n < SEGPC; ++n) {
    cxr[n] = prm[n][0]; cyr[n] = prm[n][1]; e0r[n] = prm[n][2]; e1r[n] = prm[n][3];
    vr[n] = (prm[n][4] != 0.f);
  }
  const uint4* ev = (const uint4*)exyh + (size_t)b * (HW / 4);
  const unsigned* tv = tb8 + (size_t)b * (HW / 4);
  const unsigned* sv = sd8 + (size_t)b * (HW / 4);
  int lane = tid & 63;
  int wid = tid >> 6;               // 8 waves
  int swl = (lane * 21) & 63;       // decorrelate bucket keys within a wave
  float sacc[SEGPC];
#pragma unroll
  for (int n = 0; n < SEGPC; ++n) sacc[n] = 0.f;
  // groups: 65536/batch; per split 4096; per block 8 iters of 512
  int g = split * 4096 + wid * 64 + swl;
  uint4 ee = ev[g];
  unsigned tp = tv[g];
  unsigned sp = sv[g];
  for (int it = 0; it < 8; ++it) {
    uint4 ne; unsigned ntp, nsp;
    int ng = g + 512;
    if (it < 7) { ne = ev[ng]; ntp = tv[ng]; nsp = sv[ng]; }
    unsigned ew[4] = {ee.x, ee.y, ee.z, ee.w};
#pragma unroll
    for (int k = 0; k < 4; ++k) {
      unsigned u = ew[k];
      __half2 h = *reinterpret_cast<__half2*>(&u);
      float2 e = __half22float2(h);
      int t = (int)((tp >> (8 * k)) & 255u);
#pragma unroll
      for (int n = 0; n < SEGPC; ++n) {
        if (!vr[n]) continue;
        float dx = e.x - cxr[n];
        float dy = e.y - cyr[n];
        float d = __expf(-(e0r[n] * dx * dx + e1r[n] * dy * dy));
        int key = keyof(d);
        bool pos = (t == seg0 + n + 1);
        atomicAdd(&lhist[n * KTOT + key], pos ? 65536u : 1u);
        if (pos) {
          float sd = (float)((sp >> (8 * k)) & 255u) * (1.0f / 255.0f);
          float df = sd - d;
          sacc[n] += df * df;
        }
      }
    }
    if (it < 7) { ee = ne; tp = ntp; sp = nsp; g = ng; }
  }
#pragma unroll
  for (int n = 0; n < SEGPC; ++n) {
    float v = sacc[n];
    for (int off = 32; off > 0; off >>= 1) v += __shfl_down(v, off, 64);
    if (lane == 0 && v != 0.f) atomicAdd(&seedi[b * NID + seg0 + n], v);
  }
  __syncthreads();
#pragma unroll
  for (int n = 0; n < SEGPC; ++n) {
    int gs = seg0 + n;
    if (gs >= NID) break;
    size_t base = ((size_t)(b * NID + gs) * NSPL + split) * KTOT;
    for (int k = tid; k < KTOT; k += 512) partPN[base + k] = lhist[n * KTOT + k];
  }
}

// ---------------- lovasz: combine packed partials, LDS scans, bucket-sweep ----------------
__global__ void __launch_bounds__(1024)
lovasz_kernel(const unsigned* __restrict__ partPN, const float* __restrict__ stats,
              float* __restrict__ instAcc) {
  __shared__ int histP[KTOT];
  __shared__ int histN[KTOT];
  __shared__ int PreP[KTOT + 1];
  __shared__ int PreN[KTOT + 1];
  __shared__ int scr[1024];
  __shared__ float prm[2];
  int seg = blockIdx.x;
  int tid = threadIdx.x;
  if (tid == 0) {
    Params pp = calc_params(stats + (size_t)seg * 8);
    prm[0] = pp.valid;
    prm[1] = pp.cnt;
  }
  __syncthreads();
  if (prm[0] == 0.f) {
    if (tid == 0) instAcc[seg] = 0.f;
    return;
  }
  int P = (int)prm[1];
  int Nn = HW - P;
  if (tid < KTOT) {    // KTOT=1144: threads 0..1143, one key each... plus strided tail
  }
  for (int k = tid; k < KTOT; k += 1024) {
    int sp = 0, sn = 0;
#pragma unroll
    for (int s = 0; s < NSPL; ++s) {
      unsigned v = partPN[((size_t)seg * NSPL + s) * KTOT + k];
      sp += (int)(v >> 16);
      sn += (int)(v & 0xFFFFu);
    }
    histP[k] = sp;
    histN[k] = sn;
  }
  __syncthreads();
  {
    int base = tid * 2;
    int a0 = (base < KTOT) ? histP[base] : 0;
    int a1 = (base + 1 < KTOT) ? histP[base + 1] : 0;
    scr[tid] = a0 + a1;
    __syncthreads();
    for (int off = 1; off < 1024; off <<= 1) {
      int v = scr[tid];
      int u = (tid >= off) ? scr[tid - off] : 0;
      __syncthreads();
      scr[tid] = v + u;
      __syncthreads();
    }
    int excl = (tid > 0) ? scr[tid - 1] : 0;
    if (base < KTOT) PreP[base] = excl;
    if (base + 1 < KTOT) PreP[base + 1] = excl + a0;
    if (tid == 0) PreP[KTOT] = scr[1023];
    __syncthreads();
    a0 = (base < KTOT) ? histN[base] : 0;
    a1 = (base + 1 < KTOT) ? histN[base + 1] : 0;
    scr[tid] = a0 + a1;
    __syncthreads();
    for (int off = 1; off < 1024; off <<= 1) {
      int v = scr[tid];
      int u = (tid >= off) ? scr[tid - off] : 0;
      __syncthreads();
      scr[tid] = v + u;
      __syncthreads();
    }
    excl = (tid > 0) ? scr[tid - 1] : 0;
    if (base < KTOT) PreN[base] = excl;
    if (base + 1 < KTOT) PreN[base + 1] = excl + a0;
    if (tid == 0) PreN[KTOT] = scr[1023];
    __syncthreads();
  }
  float acc = 0.f;
  for (int k = tid; k < KTOT; k += 1024) {
    int hp = histP[k], hn = histN[k];
    if ((hp | hn) == 0) continue;
    float lo, hi;
    boundsof(k, &lo, &hi);
    float m = 0.5f * (lo + hi);
    m = fminf(m, __uint_as_float(0x3F7FFFFFu));
    float tv = 1.0f - m;
    int j = keyof(tv);
    float jlo, jhi;
    boundsof(j, &jlo, &jhi);
    float den = jhi - jlo;
    float fr = (den > 0.f) ? (tv - jlo) / den : 0.5f;
    fr = fminf(fmaxf(fr, 0.f), 1.f);
    if (hp) {
      float q = (float)(Nn - PreN[j + 1]) + (1.0f - fr) * (float)histN[j];
      float a = 2.0f - 2.0f * m;
      acc += (float)hp * a / ((float)P + q);
    }
    if (hn) {
      float p = (float)PreP[j] + fr * (float)histP[j];
      int R = Nn - PreN[k + 1];
      float u0 = 1.0f / (float)(P + R);
      float u1 = 1.0f / (float)(P + R + hn);
      acc += (2.0f * m) * ((float)P - p) * (u0 - u1);
    }
  }
  float* scrf = (float*)scr;
  scrf[tid] = acc;
  __syncthreads();
  for (int s = 512; s > 0; s >>= 1) {
    if (tid < s) scrf[tid] += scrf[tid + s];
    __syncthreads();
  }
  if (tid == 0) instAcc[seg] = scrf[0];
}

// ---------------- final combine ----------------
__global__ void final_kernel(const float* __restrict__ stats, const float* __restrict__ instAcc,
                             const float* __restrict__ seediAcc, const float* __restrict__ seedbg,
                             float* __restrict__ out) {
  int b = threadIdx.x;
  __shared__ float red[64];
  float lb = 0.f;
  if (b < BATCH) {
    float sv = 0.f, si = 0.f, svar = 0.f, ssd = 0.f;
    for (int n = 0; n < NID; ++n) {
      Params pp = calc_params(stats + (size_t)(b * NID + n) * 8);
      float vf = pp.valid;
      sv += vf;
      si += vf * instAcc[b * NID + n];
      svar += vf * pp.var;
      ssd += vf * seediAcc[b * NID + n];
    }
    float obj = fmaxf(sv, 1.0f);
    lb = si / obj + 10.0f * (svar / obj) + (seedbg[b] + ssd) / (float)HW;
  }
  red[threadIdx.x] = lb;
  __syncthreads();
  for (int s = 32; s > 0; s >>= 1) {
    if (threadIdx.x < s) red[threadIdx.x] += red[threadIdx.x + s];
    __syncthreads();
  }
  if (threadIdx.x == 0) out[0] = red[0] / (float)BATCH;
}

extern "C" void kernel_launch(void* const* d_in, const int* in_sizes, int n_in,
                              void* d_out, int out_size, void* d_ws, size_t ws_size,
                              hipStream_t stream) {
  const float* pred = (const float*)d_in[0];
  const int* inst = (const int*)d_in[1];
  const int* lab = (const int*)d_in[2];
  float* out = (float*)d_out;

  // head (floats): seediAcc[240] | stats[1920] | instAcc[240] | seedbg[16]
  float* wsf = (float*)d_ws;
  float* seediAcc = wsf;
  float* stats = wsf + 240;
  float* instAcc = wsf + 2160;
  float* seedbg = wsf + 2400;
  char* p = (char*)d_ws + HEADB;
  unsigned* exyh = (unsigned*)p;            p += (size_t)BATCH * HW * 4;          // 16.78 MB
  unsigned* tb8 = (unsigned*)p;             p += (size_t)BATCH * HW;              // 4.19 MB
  unsigned* sd8 = (unsigned*)p;             p += (size_t)BATCH * HW;              // 4.19 MB
  unsigned* partPN = (unsigned*)p;          p += (size_t)NSEG * NSPL * KTOT * 4;  // 17.57 MB
  float* blockpart = (float*)p;             // 1024*112*4 = 0.46 MB; total ~43.3 MB

  hipMemsetAsync(seediAcc, 0, 240 * sizeof(float), stream);
  pre_kernel<<<PREBLK, 256, 0, stream>>>(pred, inst, lab, blockpart, exyh, tb8, sd8);
  reduce_kernel<<<dim3(NID * 7 + 1, BATCH), 64, 0, stream>>>(blockpart, stats, seedbg);
  hist_kernel<<<dim3(NSPL, 2, BATCH), 512, 0, stream>>>(exyh, tb8, sd8, stats, partPN, seediAcc);
  lovasz_kernel<<<NSEG, 1024, 0, stream>>>(partPN, stats, instAcc);
  final_kernel<<<1, 64, 0, stream>>>(stats, instAcc, seediAcc, seedbg, out);
}